// Round 17
// baseline (78.532 us; speedup 1.0000x reference)
//
#include <hip/hip_runtime.h>
#include <hip/hip_bf16.h>
#include <math.h>

typedef __attribute__((ext_vector_type(8))) short short8v;   // 8 bf16 bits
typedef __attribute__((ext_vector_type(4))) float f32x4;     // 16x16 MFMA acc

__device__ __forceinline__ unsigned short f2bf(float x) {   // prep only
    union { float f; unsigned u; } v; v.f = x;
    unsigned r = v.u + 0x7FFF + ((v.u >> 16) & 1);   // RNE
    return (unsigned short)(r >> 16);
}
__device__ __forceinline__ unsigned cvtpk(float a, float b) {
    unsigned short lo = __builtin_bit_cast(unsigned short, __float2bfloat16(a));
    unsigned short hi = __builtin_bit_cast(unsigned short, __float2bfloat16(b));
    return (unsigned)lo | ((unsigned)hi << 16);
}
__device__ __forceinline__ float fast_tanh(float x) {
    float e = __expf(2.0f * x);
    return 1.0f - 2.0f / (e + 1.0f);
}
__device__ __host__ __forceinline__ int sigma_perm(int ct, int p) {
    return 32 * (ct >> 1) + 8 * (p >> 2) + 4 * (ct & 1) + (p & 3);
}

// d_ws layout (bytes):
//   [0, 4096)                A (f32, debug only)
//   [4096 + c*53248 ...)     table copy c (c = 0..NCOPY-1):
//       +0      W1P  bf16 [8 ct][16 row][32 k]  k>=16 ZERO, sigma rows (8192B)
//       +8192   W2P  bf16 [8 ct][16 row][128 k] sigma rows            (32768B)
//       +40960  W3T  bf16 [16 col][128 k]                             (4096B)
//       +45056  MP   bf16 [8 ct][16 row][32 k]  k>=16 ZERO            (8192B)
#define WS_A       0
#define WS_TAB     4096
#define C_W1       0
#define C_W2       8192
#define C_W3       40960
#define C_MP       45056
#define COPY_BYTES 53248
#define NCOPY      32

// ---------------------------------------------------------------------------
// Prep: 65 blocks build copy 0 (R11-proven builds, relocated into copy 0).
// ---------------------------------------------------------------------------
__global__ __launch_bounds__(256) void ce_prep_kernel(
    const int* __restrict__ pilot_pos,
    const float* __restrict__ decay_param,
    const float* __restrict__ window_logits,
    const float* __restrict__ W1, const float* __restrict__ W2,
    const float* __restrict__ W3,
    char* __restrict__ ws)
{
    char* tab0 = ws + WS_TAB;
    int t = threadIdx.x;
    if (blockIdx.x != 0) {
        int i = (int)(blockIdx.x - 1) * 256 + t;
        int row = i >> 7, k = i & 127;
        int ct = row >> 4, p = row & 15;
        unsigned short* w2p = (unsigned short*)(tab0 + C_W2);
        w2p[i] = f2bf(W2[k * 128 + sigma_perm(ct, p)]);
        return;
    }
    __shared__ float win[8], Gr[64], Gi[64], wln[64], wrn[64];
    __shared__ int lefts[64], pos[8];
    __shared__ float sA[64 * 16];
    if (t < 8) {
        pos[t] = pilot_pos[t];
        win[t] = 1.0f / (1.0f + expf(-window_logits[t]));
    }
    __syncthreads();
    float decay = log1pf(expf(decay_param[0]));
    if (t < 64) {
        float gr = 0.f, gi = 0.f;
        #pragma unroll
        for (int n = 0; n < 8; ++n) {
            float ang = 6.283185307179586f * (float)(n * t) * (1.0f / 64.0f);
            gr += win[n] * cosf(ang);
            gi += win[n] * sinf(ang);
        }
        Gr[t] = gr * (1.0f / 64.0f);
        Gi[t] = gi * (1.0f / 64.0f);
        int lft = 0;
        #pragma unroll
        for (int p = 1; p < 8; ++p) if (pos[p] <= t) lft = p;
        if (lft > 6) lft = 6;
        float x0 = (float)pos[lft], x1 = (float)pos[lft + 1], fi = (float)t;
        float wl = expf(-decay * fabsf(fi - x0));
        float wr = expf(-decay * fabsf(x1 - fi));
        float wsum = wl + wr + 1e-12f;
        lefts[t] = lft; wln[t] = wl / wsum; wrn[t] = wr / wsum;
    }
    __syncthreads();
    if (t < 64) {
        float ar[8], ai[8];
        for (int p = 0; p < 8; ++p) { ar[p] = 0.f; ai[p] = 0.f; }
        for (int i = 0; i < 64; ++i) {
            int d = (i - t) & 63;
            float gr = Gr[d], gi = Gi[d];
            int lft = lefts[i];
            float wa = wln[i], wb = wrn[i];
            ar[lft]     += wa * gr;  ai[lft]     += wa * gi;
            ar[lft + 1] += wb * gr;  ai[lft + 1] += wb * gi;
        }
        float* A = (float*)(ws + WS_A);
        for (int p = 0; p < 8; ++p) {
            A[t * 16 + 2 * p]     = ar[p];
            A[t * 16 + 2 * p + 1] = ai[p];
            sA[t * 16 + 2 * p]     = ar[p];
            sA[t * 16 + 2 * p + 1] = ai[p];
        }
    }
    __syncthreads();
    unsigned short* mp = (unsigned short*)(tab0 + C_MP);
    for (int i = t; i < 8 * 16 * 32; i += 256) {
        int ct = i >> 9, rem = i & 511;
        int jl = rem >> 5, k = rem & 31;
        unsigned short v = 0;
        if (k < 16) {
            int j = ct * 16 + jl, m = j >> 1, s = j & 1;
            int p = k >> 1, u = k & 1;
            float Ar = sA[m * 16 + 2 * p], Ai = sA[m * 16 + 2 * p + 1];
            float val = (s == 0) ? ((u == 0) ? Ar : -Ai)
                                 : ((u == 0) ? Ai :  Ar);
            v = f2bf(val);
        }
        mp[i] = v;
    }
    unsigned short* w1p = (unsigned short*)(tab0 + C_W1);
    for (int i = t; i < 128 * 32; i += 256) {
        int row = i >> 5, k = i & 31;
        int ct = row >> 4, p = row & 15;
        w1p[i] = (k < 16) ? f2bf(W1[k * 128 + sigma_perm(ct, p)]) : (unsigned short)0;
    }
    unsigned short* w3t = (unsigned short*)(tab0 + C_W3);
    for (int i = t; i < 16 * 128; i += 256) {
        int col = i >> 7, k = i & 127;
        w3t[i] = f2bf(W3[k * 64 + col]);
    }
}

// ---------------------------------------------------------------------------
// Replicate copy 0 -> copies 1..NCOPY-1 (spreads hot L2 lines 32x).
// ---------------------------------------------------------------------------
__global__ __launch_bounds__(256) void ce_repl(char* __restrict__ ws)
{
    const uint4* src = (const uint4*)(ws + WS_TAB);
    uint4* dst = (uint4*)(ws + WS_TAB + (size_t)(blockIdx.x + 1) * COPY_BYTES);
    for (int i = threadIdx.x; i < COPY_BYTES / 16; i += 256)
        dst[i] = src[i];
}

// ---------------------------------------------------------------------------
// Fused kernel (R16, unchanged math): zero LDS, zero barriers, bias in MFMA
// C-operand, HW cvt, prefetch, burst epilogue. ONLY change: per-block table
// copy selection (blockIdx>>3 & mask) to spread L2 hot-line contention.
// ---------------------------------------------------------------------------
__global__ __launch_bounds__(256) void ce_fused(
    const float* __restrict__ Y, const float* __restrict__ Xp,
    const int* __restrict__ pilot_pos,
    const float* __restrict__ b1, const float* __restrict__ b2,
    const float* __restrict__ b3,
    const float* __restrict__ est_w, const float* __restrict__ alpha,
    const char* __restrict__ ws, int copy_mask,
    float* __restrict__ out, int B)
{
    const char* tab = ws + WS_TAB +
        (size_t)((blockIdx.x >> 3) & copy_mask) * COPY_BYTES;
    const unsigned short* w1p = (const unsigned short*)(tab + C_W1);
    const unsigned short* w2p = (const unsigned short*)(tab + C_W2);
    const unsigned short* w3t = (const unsigned short*)(tab + C_W3);
    const unsigned short* mp  = (const unsigned short*)(tab + C_MP);

    const int t = threadIdx.x;
    const int w = t >> 6, l = t & 63;
    const int m = l & 15, kg = l >> 4;
    const int tl = kg >> 1, pg = kg & 1;
    const long base = (long)blockIdx.x * 128 + w * 32;

    typedef union { unsigned u[4]; short8v v; } pk_t;
    const f32x4 z4 = {0.f, 0.f, 0.f, 0.f};

    // ---- gather (longest latency: issue first) ----
    long e_g = base + tl * 16 + m;
    long e_gc = (e_g < B) ? e_g : (long)(B - 1);
    const float* yrow = Y + e_gc * 128;
    const float4* xr = (const float4*)(Xp + e_gc * 16 + pg * 8);
    int p0 = pg * 4;
    float2 y0 = *(const float2*)(yrow + pilot_pos[p0 + 0] * 2);
    float2 y1 = *(const float2*)(yrow + pilot_pos[p0 + 1] * 2);
    float2 y2 = *(const float2*)(yrow + pilot_pos[p0 + 2] * 2);
    float2 y3 = *(const float2*)(yrow + pilot_pos[p0 + 3] * 2);
    float4 x0 = xr[0], x1 = xr[1];

    // ---- W1 fragments preloaded under gather latency ----
    short8v wf1[8];
    #pragma unroll
    for (int ct = 0; ct < 8; ++ct)
        wf1[ct] = *(const short8v*)(w1p + (ct * 16 + m) * 32 + kg * 8);

    // ---- LS compute ----
    float lsv[8];
    {
        float inv;
        inv = 1.0f / (x0.x * x0.x + x0.y * x0.y);
        lsv[0] = (y0.x * x0.x + y0.y * x0.y) * inv;
        lsv[1] = (y0.y * x0.x - y0.x * x0.y) * inv;
        inv = 1.0f / (x0.z * x0.z + x0.w * x0.w);
        lsv[2] = (y1.x * x0.z + y1.y * x0.w) * inv;
        lsv[3] = (y1.y * x0.z - y1.x * x0.w) * inv;
        inv = 1.0f / (x1.x * x1.x + x1.y * x1.y);
        lsv[4] = (y2.x * x1.x + y2.y * x1.y) * inv;
        lsv[5] = (y2.y * x1.x - y2.x * x1.y) * inv;
        inv = 1.0f / (x1.z * x1.z + x1.w * x1.w);
        lsv[6] = (y3.x * x1.z + y3.y * x1.w) * inv;
        lsv[7] = (y3.y * x1.z - y3.x * x1.w) * inv;
    }
    pk_t px;
    px.u[0] = cvtpk(lsv[0], lsv[1]);
    px.u[1] = cvtpk(lsv[2], lsv[3]);
    px.u[2] = cvtpk(lsv[4], lsv[5]);
    px.u[3] = cvtpk(lsv[6], lsv[7]);
    short8v xb = px.v;
    short8v xb1;
    {
        union { short8v v; int i[4]; } ua, ub;
        ua.v = xb;
        #pragma unroll
        for (int q = 0; q < 4; ++q) ub.i[q] = __shfl_xor(ua.i[q], 32);
        xb1 = ub.v;
    }

    // ---- Layer 1: bias as C-operand ----
    pk_t h1a[4], h1b[4];
    #pragma unroll
    for (int ks = 0; ks < 4; ++ks) {
        #pragma unroll
        for (int half = 0; half < 2; ++half) {
            int ct = 2 * ks + half;
            float4 bv = *(const float4*)(b1 + ks * 32 + kg * 8 + half * 4);
            f32x4 cin = { bv.x, bv.y, bv.z, bv.w };
            f32x4 aA = __builtin_amdgcn_mfma_f32_16x16x32_bf16(wf1[ct], xb,  cin, 0, 0, 0);
            f32x4 aB = __builtin_amdgcn_mfma_f32_16x16x32_bf16(wf1[ct], xb1, cin, 0, 0, 0);
            h1a[ks].u[2 * half]     = cvtpk(fmaxf(aA[0], 0.f), fmaxf(aA[1], 0.f));
            h1a[ks].u[2 * half + 1] = cvtpk(fmaxf(aA[2], 0.f), fmaxf(aA[3], 0.f));
            h1b[ks].u[2 * half]     = cvtpk(fmaxf(aB[0], 0.f), fmaxf(aB[1], 0.f));
            h1b[ks].u[2 * half + 1] = cvtpk(fmaxf(aB[2], 0.f), fmaxf(aB[3], 0.f));
        }
    }

    // ---- Layer 2: bias C-init, group-prefetched fragments ----
    f32x4 a2a[8], a2b[8];
    #pragma unroll
    for (int ct = 0; ct < 8; ++ct) {
        float4 bv = *(const float4*)(b2 + 32 * (ct >> 1) + 8 * kg + 4 * (ct & 1));
        f32x4 cin = { bv.x, bv.y, bv.z, bv.w };
        a2a[ct] = cin; a2b[ct] = cin;
    }
    #pragma unroll
    for (int ks = 0; ks < 4; ++ks) {
        short8v wb[8];
        #pragma unroll
        for (int ct = 0; ct < 8; ++ct)
            wb[ct] = *(const short8v*)(w2p + (ct * 16 + m) * 128 + ks * 32 + kg * 8);
        short8v hfa = h1a[ks].v, hfb = h1b[ks].v;
        #pragma unroll
        for (int ct = 0; ct < 8; ++ct) {
            a2a[ct] = __builtin_amdgcn_mfma_f32_16x16x32_bf16(wb[ct], hfa, a2a[ct], 0, 0, 0);
            a2b[ct] = __builtin_amdgcn_mfma_f32_16x16x32_bf16(wb[ct], hfb, a2b[ct], 0, 0, 0);
        }
    }

    // ---- repack -> h2 (bias already in acc) ----
    pk_t h2a[4], h2b[4];
    #pragma unroll
    for (int ks = 0; ks < 4; ++ks) {
        #pragma unroll
        for (int half = 0; half < 2; ++half) {
            int ct = 2 * ks + half;
            h2a[ks].u[2 * half]     = cvtpk(fmaxf(a2a[ct][0], 0.f), fmaxf(a2a[ct][1], 0.f));
            h2a[ks].u[2 * half + 1] = cvtpk(fmaxf(a2a[ct][2], 0.f), fmaxf(a2a[ct][3], 0.f));
            h2b[ks].u[2 * half]     = cvtpk(fmaxf(a2b[ct][0], 0.f), fmaxf(a2b[ct][1], 0.f));
            h2b[ks].u[2 * half + 1] = cvtpk(fmaxf(a2b[ct][2], 0.f), fmaxf(a2b[ct][3], 0.f));
        }
    }

    // ---- Layer 3: b3 folded as C-init ----
    float4 b3c = *(const float4*)(b3 + 4 * kg);
    f32x4 cin3 = { b3c.x, b3c.y, b3c.z, b3c.w };
    f32x4 acc3a = cin3, acc3b = cin3;
    #pragma unroll
    for (int ks = 0; ks < 4; ++ks) {
        short8v wf = *(const short8v*)(w3t + m * 128 + ks * 32 + kg * 8);
        acc3a = __builtin_amdgcn_mfma_f32_16x16x32_bf16(wf, h2a[ks].v, acc3a, 0, 0, 0);
        acc3b = __builtin_amdgcn_mfma_f32_16x16x32_bf16(wf, h2b[ks].v, acc3b, 0, 0, 0);
    }

    // ---- comb (R11-verified lane algebra; biases pre-folded) ----
    pk_t myv;
    {
        float w0 = est_w[0];
        float al = fminf(fmaxf(alpha[0], 0.f), 1.f);
        float oma = 1.0f - al;
        bool low = (kg < 2);
        #pragma unroll
        for (int r = 0; r < 4; ++r) {
            float s0 = __shfl_xor(acc3a[r], 32);
            float s1 = __shfl_xor(acc3b[r], 32);
            float olow  = low ? acc3a[r] : s1;
            float ohigh = low ? s0 : acc3b[r];
            float cr = al * (lsv[2 * r] * w0)     + oma * fast_tanh(olow);
            float ci = al * (lsv[2 * r + 1] * w0) + oma * fast_tanh(ohigh);
            myv.u[r] = cvtpk(cr, ci);
        }
    }
    short8v vb0 = myv.v;
    short8v vb1;
    {
        union { short8v v; int i[4]; } ua, ub;
        ua.v = myv.v;
        #pragma unroll
        for (int q = 0; q < 4; ++q) ub.i[q] = __shfl_xor(ua.i[q], 32);
        vb1 = ub.v;
    }

    // ---- epilogue: prefetch MP, MFMA burst, then STORE BURST per tile ----
    short8v mf[8];
    #pragma unroll
    for (int ct = 0; ct < 8; ++ct)
        mf[ct] = *(const short8v*)(mp + (ct * 16 + m) * 32 + kg * 8);

    long e0 = base + m, e1 = base + 16 + m;
    float* orow0 = out + e0 * 128;
    float* orow1 = out + e1 * 128;
    {
        f32x4 eacc[8];
        #pragma unroll
        for (int ct = 0; ct < 8; ++ct)
            eacc[ct] = __builtin_amdgcn_mfma_f32_16x16x32_bf16(mf[ct], vb0, z4, 0, 0, 0);
        if (e0 < B) {
            #pragma unroll
            for (int ct = 0; ct < 8; ++ct) {
                float4 st = { eacc[ct][0], eacc[ct][1], eacc[ct][2], eacc[ct][3] };
                *(float4*)(orow0 + ct * 16 + kg * 4) = st;
            }
        }
        #pragma unroll
        for (int ct = 0; ct < 8; ++ct)
            eacc[ct] = __builtin_amdgcn_mfma_f32_16x16x32_bf16(mf[ct], vb1, z4, 0, 0, 0);
        if (e1 < B) {
            #pragma unroll
            for (int ct = 0; ct < 8; ++ct) {
                float4 st = { eacc[ct][0], eacc[ct][1], eacc[ct][2], eacc[ct][3] };
                *(float4*)(orow1 + ct * 16 + kg * 4) = st;
            }
        }
    }
}

extern "C" void kernel_launch(void* const* d_in, const int* in_sizes, int n_in,
                              void* d_out, int out_size, void* d_ws, size_t ws_size,
                              hipStream_t stream) {
    const float* Y             = (const float*)d_in[0];
    const float* Xp            = (const float*)d_in[1];
    const int*   pilot_pos     = (const int*)d_in[2];
    const float* W1            = (const float*)d_in[3];
    const float* b1            = (const float*)d_in[4];
    const float* W2            = (const float*)d_in[5];
    const float* b2            = (const float*)d_in[6];
    const float* W3            = (const float*)d_in[7];
    const float* b3            = (const float*)d_in[8];
    const float* est_w         = (const float*)d_in[9];
    const float* alpha         = (const float*)d_in[10];
    const float* decay_param   = (const float*)d_in[11];
    const float* window_logits = (const float*)d_in[12];
    float* out = (float*)d_out;
    char* ws = (char*)d_ws;

    int B = in_sizes[0] / 128;

    hipLaunchKernelGGL(ce_prep_kernel, dim3(65), dim3(256), 0, stream,
                       pilot_pos, decay_param, window_logits, W1, W2, W3, ws);

    size_t need = (size_t)WS_TAB + (size_t)NCOPY * COPY_BYTES;
    int copy_mask = 0;
    if (ws_size >= need) {
        copy_mask = NCOPY - 1;
        hipLaunchKernelGGL(ce_repl, dim3(NCOPY - 1), dim3(256), 0, stream, ws);
    }

    int grid = (B + 127) / 128;
    hipLaunchKernelGGL(ce_fused, dim3(grid), dim3(256), 0, stream,
                       Y, Xp, pilot_pos, b1, b2, b3, est_w, alpha,
                       ws, copy_mask, out, B);
}

// Round 18
// 58.803 us; speedup vs baseline: 1.3355x; 1.3355x over previous
//
#include <hip/hip_runtime.h>
#include <hip/hip_bf16.h>
#include <math.h>

typedef __attribute__((ext_vector_type(8))) short short8v;   // 8 bf16 bits
typedef __attribute__((ext_vector_type(4))) float f32x4;     // 16x16 MFMA acc

__device__ __forceinline__ unsigned short f2bf(float x) {   // prep only
    union { float f; unsigned u; } v; v.f = x;
    unsigned r = v.u + 0x7FFF + ((v.u >> 16) & 1);   // RNE
    return (unsigned short)(r >> 16);
}
__device__ __forceinline__ unsigned cvtpk(float a, float b) {
    unsigned short lo = __builtin_bit_cast(unsigned short, __float2bfloat16(a));
    unsigned short hi = __builtin_bit_cast(unsigned short, __float2bfloat16(b));
    return (unsigned)lo | ((unsigned)hi << 16);
}
__device__ __forceinline__ float fast_tanh(float x) {
    float e = __expf(2.0f * x);
    return 1.0f - 2.0f / (e + 1.0f);
}
__device__ __host__ __forceinline__ int sigma_perm(int ct, int p) {
    return 32 * (ct >> 1) + 8 * (p >> 2) + 4 * (ct & 1) + (p & 3);
}

// d_ws: [0,4096) scratch A; [4096, ...) PADDED table blob (shorts):
//   T_W1  [128 row][40]  k<16 = W1[k][sigma], k 16..31 ZERO  (5120 sh)
//   T_W2  [128 row][136] k<128 = W2[k][sigma]               (17408 sh)
//   T_W3  [16 col][136]  k<128 = W3[k][col]                 (2176 sh)
//   T_MP  [128 row][40]  k<16 = MP val, k 16..31 ZERO       (5120 sh)
#define WS_TAB  4096
#define T_W1    0
#define T_W2    5120
#define T_W3    22528
#define T_MP    24704
#define T_SH    29824          // total shorts = 59648 B = 3728 uint4

// ---------------------------------------------------------------------------
// Prep: block 0 -> A/MP/W1/W3 (padded); blocks 1..64 -> W2 (padded).
// Values byte-identical to R11-proven builds, only strides padded.
// ---------------------------------------------------------------------------
__global__ __launch_bounds__(256) void ce_prep_kernel(
    const int* __restrict__ pilot_pos,
    const float* __restrict__ decay_param,
    const float* __restrict__ window_logits,
    const float* __restrict__ W1, const float* __restrict__ W2,
    const float* __restrict__ W3,
    char* __restrict__ ws)
{
    unsigned short* tab = (unsigned short*)(ws + WS_TAB);
    int t = threadIdx.x;
    if (blockIdx.x != 0) {
        int i = (int)(blockIdx.x - 1) * 256 + t;     // [0, 16384)
        int row = i >> 7, k = i & 127;
        int ct = row >> 4, p = row & 15;
        tab[T_W2 + row * 136 + k] = f2bf(W2[k * 128 + sigma_perm(ct, p)]);
        return;
    }
    __shared__ float win[8], Gr[64], Gi[64], wln[64], wrn[64];
    __shared__ int lefts[64], pos[8];
    __shared__ float sA[64 * 16];
    if (t < 8) {
        pos[t] = pilot_pos[t];
        win[t] = 1.0f / (1.0f + expf(-window_logits[t]));
    }
    __syncthreads();
    float decay = log1pf(expf(decay_param[0]));
    if (t < 64) {
        float gr = 0.f, gi = 0.f;
        #pragma unroll
        for (int n = 0; n < 8; ++n) {
            float ang = 6.283185307179586f * (float)(n * t) * (1.0f / 64.0f);
            gr += win[n] * cosf(ang);
            gi += win[n] * sinf(ang);
        }
        Gr[t] = gr * (1.0f / 64.0f);
        Gi[t] = gi * (1.0f / 64.0f);
        int lft = 0;
        #pragma unroll
        for (int p = 1; p < 8; ++p) if (pos[p] <= t) lft = p;
        if (lft > 6) lft = 6;
        float x0 = (float)pos[lft], x1 = (float)pos[lft + 1], fi = (float)t;
        float wl = expf(-decay * fabsf(fi - x0));
        float wr = expf(-decay * fabsf(x1 - fi));
        float wsum = wl + wr + 1e-12f;
        lefts[t] = lft; wln[t] = wl / wsum; wrn[t] = wr / wsum;
    }
    __syncthreads();
    if (t < 64) {
        float ar[8], ai[8];
        for (int p = 0; p < 8; ++p) { ar[p] = 0.f; ai[p] = 0.f; }
        for (int i = 0; i < 64; ++i) {
            int d = (i - t) & 63;
            float gr = Gr[d], gi = Gi[d];
            int lft = lefts[i];
            float wa = wln[i], wb = wrn[i];
            ar[lft]     += wa * gr;  ai[lft]     += wa * gi;
            ar[lft + 1] += wb * gr;  ai[lft + 1] += wb * gi;
        }
        for (int p = 0; p < 8; ++p) {
            sA[t * 16 + 2 * p]     = ar[p];
            sA[t * 16 + 2 * p + 1] = ai[p];
        }
    }
    __syncthreads();
    // MP padded [row][40]
    for (int i = t; i < 128 * 32; i += 256) {
        int row = i >> 5, k = i & 31;
        unsigned short v = 0;
        if (k < 16) {
            int j = row, mm = j >> 1, s = j & 1;
            int ct = row >> 4; (void)ct;
            int p = k >> 1, u = k & 1;
            float Ar = sA[mm * 16 + 2 * p], Ai = sA[mm * 16 + 2 * p + 1];
            float val = (s == 0) ? ((u == 0) ? Ar : -Ai)
                                 : ((u == 0) ? Ai :  Ar);
            v = f2bf(val);
        }
        tab[T_MP + row * 40 + k] = v;
    }
    // W1 padded [row][40]
    for (int i = t; i < 128 * 32; i += 256) {
        int row = i >> 5, k = i & 31;
        int ct = row >> 4, p = row & 15;
        tab[T_W1 + row * 40 + k] =
            (k < 16) ? f2bf(W1[k * 128 + sigma_perm(ct, p)]) : (unsigned short)0;
    }
    // W3 padded [col][136]
    for (int i = t; i < 16 * 128; i += 256) {
        int col = i >> 7, k = i & 127;
        tab[T_W3 + col * 136 + k] = f2bf(W3[k * 64 + col]);
    }
}

// ---------------------------------------------------------------------------
// Fused kernel: single-tile register MLP (R10-proven math) with weights in
// LDS (one-shot 59.6KB stage per 512-thr block; gather issued before the
// stage so HBM latency hides under it). Zero barriers after the stage one.
// ---------------------------------------------------------------------------
__global__ __launch_bounds__(512) void ce_fused(
    const float* __restrict__ Y, const float* __restrict__ Xp,
    const int* __restrict__ pilot_pos,
    const float* __restrict__ b1, const float* __restrict__ b2,
    const float* __restrict__ b3,
    const float* __restrict__ est_w, const float* __restrict__ alpha,
    const char* __restrict__ ws,
    float* __restrict__ out, int B)
{
    __shared__ unsigned short sT[T_SH];          // 59648 B

    const int t = threadIdx.x;
    const int w = t >> 6, l = t & 63;
    const int m = l & 15, kg = l >> 4;
    const long e = (long)blockIdx.x * 128 + w * 16 + m;
    const long ec = (e < B) ? e : (long)(B - 1);

    typedef union { unsigned u[4]; short8v v; } pk_t;
    const f32x4 z4 = {0.f, 0.f, 0.f, 0.f};

    // ---- gather issued FIRST (lanes kg<2), latency hides under staging ----
    float2 y0, y1, y2, y3;
    float4 x0, x1;
    const bool act = (kg < 2);
    if (act) {
        const float* yrow = Y + ec * 128;
        const float4* xr = (const float4*)(Xp + ec * 16 + kg * 8);
        int p0 = kg * 4;
        y0 = *(const float2*)(yrow + pilot_pos[p0 + 0] * 2);
        y1 = *(const float2*)(yrow + pilot_pos[p0 + 1] * 2);
        y2 = *(const float2*)(yrow + pilot_pos[p0 + 2] * 2);
        y3 = *(const float2*)(yrow + pilot_pos[p0 + 3] * 2);
        x0 = xr[0]; x1 = xr[1];
    }

    // ---- stage the whole padded table to LDS (3728 uint4 / 512 thr) ----
    {
        const uint4* src = (const uint4*)(ws + WS_TAB);
        uint4* dst = (uint4*)sT;
        for (int i = t; i < T_SH / 8; i += 512) dst[i] = src[i];
    }

    // ---- LS compute (waits on gather while staging is in flight) ----
    float lsv[8];
    short8v xb = {0, 0, 0, 0, 0, 0, 0, 0};
    if (act) {
        float inv;
        inv = 1.0f / (x0.x * x0.x + x0.y * x0.y);
        lsv[0] = (y0.x * x0.x + y0.y * x0.y) * inv;
        lsv[1] = (y0.y * x0.x - y0.x * x0.y) * inv;
        inv = 1.0f / (x0.z * x0.z + x0.w * x0.w);
        lsv[2] = (y1.x * x0.z + y1.y * x0.w) * inv;
        lsv[3] = (y1.y * x0.z - y1.x * x0.w) * inv;
        inv = 1.0f / (x1.x * x1.x + x1.y * x1.y);
        lsv[4] = (y2.x * x1.x + y2.y * x1.y) * inv;
        lsv[5] = (y2.y * x1.x - y2.x * x1.y) * inv;
        inv = 1.0f / (x1.z * x1.z + x1.w * x1.w);
        lsv[6] = (y3.x * x1.z + y3.y * x1.w) * inv;
        lsv[7] = (y3.y * x1.z - y3.x * x1.w) * inv;
        pk_t px;
        px.u[0] = cvtpk(lsv[0], lsv[1]);
        px.u[1] = cvtpk(lsv[2], lsv[3]);
        px.u[2] = cvtpk(lsv[4], lsv[5]);
        px.u[3] = cvtpk(lsv[6], lsv[7]);
        xb = px.v;
    }
    __syncthreads();   // staging complete

    // ---- Layer 1: bias as C-operand, weights from LDS ----
    pk_t h1[4];
    #pragma unroll
    for (int ks = 0; ks < 4; ++ks) {
        #pragma unroll
        for (int half = 0; half < 2; ++half) {
            int ct = 2 * ks + half;
            float4 bv = *(const float4*)(b1 + ks * 32 + kg * 8 + half * 4);
            f32x4 cin = { bv.x, bv.y, bv.z, bv.w };
            short8v wf = *(const short8v*)(sT + T_W1 + (ct * 16 + m) * 40 + kg * 8);
            f32x4 acc = __builtin_amdgcn_mfma_f32_16x16x32_bf16(wf, xb, cin, 0, 0, 0);
            h1[ks].u[2 * half]     = cvtpk(fmaxf(acc[0], 0.f), fmaxf(acc[1], 0.f));
            h1[ks].u[2 * half + 1] = cvtpk(fmaxf(acc[2], 0.f), fmaxf(acc[3], 0.f));
        }
    }

    // ---- Layer 2: bias C-init ----
    f32x4 a2[8];
    #pragma unroll
    for (int ct = 0; ct < 8; ++ct) {
        float4 bv = *(const float4*)(b2 + 32 * (ct >> 1) + 8 * kg + 4 * (ct & 1));
        f32x4 cin = { bv.x, bv.y, bv.z, bv.w };
        a2[ct] = cin;
    }
    #pragma unroll
    for (int ks = 0; ks < 4; ++ks) {
        short8v hf = h1[ks].v;
        #pragma unroll
        for (int ct = 0; ct < 8; ++ct) {
            short8v wf = *(const short8v*)(sT + T_W2 + (ct * 16 + m) * 136 + ks * 32 + kg * 8);
            a2[ct] = __builtin_amdgcn_mfma_f32_16x16x32_bf16(wf, hf, a2[ct], 0, 0, 0);
        }
    }

    // ---- repack -> h2 ----
    pk_t h2[4];
    #pragma unroll
    for (int ks = 0; ks < 4; ++ks) {
        #pragma unroll
        for (int half = 0; half < 2; ++half) {
            int ct = 2 * ks + half;
            h2[ks].u[2 * half]     = cvtpk(fmaxf(a2[ct][0], 0.f), fmaxf(a2[ct][1], 0.f));
            h2[ks].u[2 * half + 1] = cvtpk(fmaxf(a2[ct][2], 0.f), fmaxf(a2[ct][3], 0.f));
        }
    }

    // ---- Layer 3: b3 folded as C-init ----
    float4 b3c = *(const float4*)(b3 + 4 * kg);
    f32x4 acc3 = { b3c.x, b3c.y, b3c.z, b3c.w };
    #pragma unroll
    for (int ks = 0; ks < 4; ++ks) {
        short8v wf = *(const short8v*)(sT + T_W3 + m * 136 + ks * 32 + kg * 8);
        acc3 = __builtin_amdgcn_mfma_f32_16x16x32_bf16(wf, h2[ks].v, acc3, 0, 0, 0);
    }

    // ---- comb (R10-proven lane algebra; biases pre-folded) ----
    pk_t myv;
    myv.u[0] = 0; myv.u[1] = 0; myv.u[2] = 0; myv.u[3] = 0;
    {
        float o0 = __shfl_down(acc3[0], 32);
        float o1 = __shfl_down(acc3[1], 32);
        float o2 = __shfl_down(acc3[2], 32);
        float o3 = __shfl_down(acc3[3], 32);
        float w0 = est_w[0];
        float al = fminf(fmaxf(alpha[0], 0.f), 1.f);
        float oma = 1.0f - al;
        if (act) {
            float olo[4] = { acc3[0], acc3[1], acc3[2], acc3[3] };
            float ohi[4] = { o0, o1, o2, o3 };
            #pragma unroll
            for (int r = 0; r < 4; ++r) {
                float cr = al * (lsv[2 * r] * w0)     + oma * fast_tanh(olo[r]);
                float ci = al * (lsv[2 * r + 1] * w0) + oma * fast_tanh(ohi[r]);
                myv.u[r] = cvtpk(cr, ci);
            }
        }
    }
    short8v vb = myv.v;   // kg>=2 lanes: MP rows k>=16 are ZERO -> harmless

    // ---- epilogue: MP-MFMA burst + store burst ----
    if (e < B) {
        float* orow = out + e * 128;
        f32x4 eacc[8];
        #pragma unroll
        for (int ct = 0; ct < 8; ++ct) {
            short8v mf = *(const short8v*)(sT + T_MP + (ct * 16 + m) * 40 + kg * 8);
            eacc[ct] = __builtin_amdgcn_mfma_f32_16x16x32_bf16(mf, vb, z4, 0, 0, 0);
        }
        #pragma unroll
        for (int ct = 0; ct < 8; ++ct) {
            float4 st = { eacc[ct][0], eacc[ct][1], eacc[ct][2], eacc[ct][3] };
            *(float4*)(orow + ct * 16 + kg * 4) = st;
        }
    }
}

extern "C" void kernel_launch(void* const* d_in, const int* in_sizes, int n_in,
                              void* d_out, int out_size, void* d_ws, size_t ws_size,
                              hipStream_t stream) {
    const float* Y             = (const float*)d_in[0];
    const float* Xp            = (const float*)d_in[1];
    const int*   pilot_pos     = (const int*)d_in[2];
    const float* W1            = (const float*)d_in[3];
    const float* b1            = (const float*)d_in[4];
    const float* W2            = (const float*)d_in[5];
    const float* b2            = (const float*)d_in[6];
    const float* W3            = (const float*)d_in[7];
    const float* b3            = (const float*)d_in[8];
    const float* est_w         = (const float*)d_in[9];
    const float* alpha         = (const float*)d_in[10];
    const float* decay_param   = (const float*)d_in[11];
    const float* window_logits = (const float*)d_in[12];
    float* out = (float*)d_out;
    char* ws = (char*)d_ws;

    int B = in_sizes[0] / 128;

    hipLaunchKernelGGL(ce_prep_kernel, dim3(65), dim3(256), 0, stream,
                       pilot_pos, decay_param, window_logits, W1, W2, W3, ws);
    int grid = (B + 127) / 128;
    hipLaunchKernelGGL(ce_fused, dim3(grid), dim3(512), 0, stream,
                       Y, Xp, pilot_pos, b1, b2, b3, est_w, alpha,
                       ws, out, B);
}